// Round 17
// baseline (272.867 us; speedup 1.0000x reference)
//
#include <hip/hip_runtime.h>
#include <math.h>
#include <type_traits>

#define NN 4096
#define NE 131072

typedef short short8 __attribute__((ext_vector_type(8)));
typedef float f32x4 __attribute__((ext_vector_type(4)));
typedef float f32x2 __attribute__((ext_vector_type(2)));
typedef unsigned short u16;

__device__ __forceinline__ float lrelu_f(float x) { return x > 0.0f ? x : 0.01f * x; }

__device__ __forceinline__ u16 f2bf(float x) {
  unsigned int u = __float_as_uint(x);
  unsigned int r = (u + 0x7FFF + ((u >> 16) & 1)) >> 16;   // RNE
  return (u16)r;
}
__device__ __forceinline__ float bf2f(u16 b) { return __uint_as_float(((unsigned int)b) << 16); }

__device__ __forceinline__ void gload_lds16(const u16* g, u16* l) {
  __builtin_amdgcn_global_load_lds((const __attribute__((address_space(1))) void*)g,
                                   (__attribute__((address_space(3))) void*)l, 16, 0, 0);
}

// ---------------- batched weight transpose+split (all 3 layers, one launch) ----------------
__global__ __launch_bounds__(256) void wtrans_all_kernel(
    const float* __restrict__ W1, const float* __restrict__ W2, const float* __restrict__ W3,
    u16* __restrict__ w1h, u16* __restrict__ w1l,
    u16* __restrict__ w2h, u16* __restrict__ w2l,
    u16* __restrict__ w3h, u16* __restrict__ w3l) {
  __shared__ u16 th[32][33], tl[32][33];
  const float* W; u16 *oh, *ol; int K, P, bp, bk;
  int bx = blockIdx.x;
  if (bx < 32)      { W = W1; oh = w1h; ol = w1l; K = 128; P = 256; int b = bx;      bp = b & 7; bk = b >> 3; }
  else if (bx < 64) { W = W2; oh = w2h; ol = w2l; K = 256; P = 128; int b = bx - 32; bp = b & 3; bk = b >> 2; }
  else              { W = W3; oh = w3h; ol = w3l; K = 128; P = 64;  int b = bx - 64; bp = b & 1; bk = b >> 1; }
  int t = threadIdx.x, tx = t & 31, ty8 = t >> 5;
  #pragma unroll
  for (int r = 0; r < 4; ++r) {
    int k = bk * 32 + ty8 + r * 8;
    int p = bp * 32 + tx;
    float x = W[(size_t)k * P + p];
    u16 hi = f2bf(x);
    th[ty8 + r * 8][tx] = hi;
    tl[ty8 + r * 8][tx] = f2bf(x - bf2f(hi));
  }
  __syncthreads();
  #pragma unroll
  for (int r = 0; r < 4; ++r) {
    int p = bp * 32 + ty8 + r * 8;
    int k = bk * 32 + tx;
    oh[(size_t)p * K + k] = th[tx][ty8 + r * 8];
    ol[(size_t)p * K + k] = tl[tx][ty8 + r * 8];
  }
}

// ---------------- MFMA GEMM: O = act(A fp32) @ WT^T + bias; optional fused row-normalize ----
template<int K, int P, bool RELU, bool NORM>
__global__ __launch_bounds__(256) void mgemm_kernel(
    const float* __restrict__ A,
    const u16* __restrict__ WThi, const u16* __restrict__ WTlo,
    const float* __restrict__ bias, float* __restrict__ O) {
  constexpr int KC = K / 32;
  __shared__ float ldsn[4][16];
  int w = threadIdx.x >> 6, l = threadIdx.x & 63;
  int lr = l & 15, lk = l >> 4;
  int i0 = blockIdx.x * 16;
  int p0 = blockIdx.y * 64 + w * 16;
  const float* ar_ = A + (size_t)(i0 + lr) * K + lk * 8;
  const u16* brh = WThi + (size_t)(p0 + lr) * K + lk * 8;
  const u16* brl = WTlo + (size_t)(p0 + lr) * K + lk * 8;
  f32x4 ahh = {0.f, 0.f, 0.f, 0.f};
  f32x4 ahl = {0.f, 0.f, 0.f, 0.f};
  f32x4 alh = {0.f, 0.f, 0.f, 0.f};
  #pragma unroll
  for (int c = 0; c < KC; ++c) {
    f32x4 a0 = *(const f32x4*)(ar_ + 32 * c);
    f32x4 a1 = *(const f32x4*)(ar_ + 32 * c + 4);
    float av[8] = {a0[0], a0[1], a0[2], a0[3], a1[0], a1[1], a1[2], a1[3]};
    short8 Ah, Al;
    #pragma unroll
    for (int j = 0; j < 8; ++j) {
      float x = av[j];
      if (RELU) x = fmaxf(x, 0.0f);
      u16 hi = f2bf(x);
      Ah[j] = (short)hi;
      Al[j] = (short)f2bf(x - bf2f(hi));
    }
    short8 Bh = *(const short8*)(brh + 32 * c);
    short8 Bl = *(const short8*)(brl + 32 * c);
    ahh = __builtin_amdgcn_mfma_f32_16x16x32_bf16(Ah, Bh, ahh, 0, 0, 0);
    ahl = __builtin_amdgcn_mfma_f32_16x16x32_bf16(Ah, Bl, ahl, 0, 0, 0);
    alh = __builtin_amdgcn_mfma_f32_16x16x32_bf16(Al, Bh, alh, 0, 0, 0);
  }
  int p = p0 + lr;
  float bv = bias[p];
  float ov[4];
  #pragma unroll
  for (int q = 0; q < 4; ++q) ov[q] = ahh[q] + ahl[q] + alh[q] + bv;

  if (NORM) {
    float sq[4];
    #pragma unroll
    for (int q = 0; q < 4; ++q) {
      float s = ov[q] * ov[q];
      #pragma unroll
      for (int m = 1; m < 16; m <<= 1) s += __shfl_xor(s, m);
      sq[q] = s;
    }
    if (lr == 0) {
      #pragma unroll
      for (int q = 0; q < 4; ++q) ldsn[w][4 * lk + q] = sq[q];
    }
    __syncthreads();
    #pragma unroll
    for (int q = 0; q < 4; ++q) {
      int row = 4 * lk + q;
      float n2 = ldsn[0][row] + ldsn[1][row] + ldsn[2][row] + ldsn[3][row];
      float nf = 1.0f / fmaxf(sqrtf(n2), 1e-12f);
      int i = i0 + row;
      O[(size_t)i * P + p] = ov[q] * nf;
    }
  } else {
    #pragma unroll
    for (int q = 0; q < 4; ++q) {
      int i = i0 + 4 * lk + q;
      O[(size_t)i * P + p] = ov[q];
    }
  }
}

// ---------------- fused prep: rowstats + colsum + bf16 split + transpose ----------------
template<int DH>
__global__ __launch_bounds__(256) void prep_kernel(const float* __restrict__ h,
    const float* __restrict__ aw, float* __restrict__ al, float* __restrict__ ar,
    float* __restrict__ inv, float* __restrict__ cs,
    u16* __restrict__ hhi, u16* __restrict__ hlo, u16* __restrict__ hT) {
  constexpr int CPT = DH / 16;
  __shared__ u16 tile[16][DH + 8];
  __shared__ float ldsp[4][DH];
  int t = threadIdx.x;
  int w = t >> 6, l = t & 63;
  int rw = l >> 4;
  int row = w * 4 + rw;
  int tcol = l & 15;
  int i = blockIdx.x * 16 + row;
  int c0 = tcol * CPT;

  float v[CPT];
  const float* hr = h + (size_t)i * DH + c0;
  #pragma unroll
  for (int k = 0; k < CPT; k += 4) {
    f32x4 x = *(const f32x4*)(hr + k);
    v[k] = x[0]; v[k + 1] = x[1]; v[k + 2] = x[2]; v[k + 3] = x[3];
  }
  float s2 = 0.f, sl = 0.f, sr = 0.f;
  #pragma unroll
  for (int k = 0; k < CPT; ++k) {
    s2 = fmaf(v[k], v[k], s2);
    sl = fmaf(v[k], aw[c0 + k], sl);
    sr = fmaf(v[k], aw[DH + c0 + k], sr);
  }
  #pragma unroll
  for (int m = 1; m < 16; m <<= 1) {
    s2 += __shfl_xor(s2, m);
    sl += __shfl_xor(sl, m);
    sr += __shfl_xor(sr, m);
  }
  if (tcol == 0) { al[i] = sl; ar[i] = sr; inv[i] = rsqrtf(s2); }

  short8 hs[CPT / 8], ls[CPT / 8];
  #pragma unroll
  for (int k = 0; k < CPT; ++k) {
    float x = v[k];
    u16 hi = f2bf(x);
    hs[k / 8][k & 7] = (short)hi;
    ls[k / 8][k & 7] = (short)f2bf(x - bf2f(hi));
  }
  #pragma unroll
  for (int b = 0; b < CPT / 8; ++b) {
    *(short8*)&hhi[(size_t)i * DH + c0 + b * 8] = hs[b];
    *(short8*)&hlo[(size_t)i * DH + c0 + b * 8] = ls[b];
    *(short8*)&tile[row][c0 + b * 8] = hs[b];
  }
  float colp[CPT];
  #pragma unroll
  for (int k = 0; k < CPT; ++k) {
    float s = v[k];
    s += __shfl_xor(s, 16);
    s += __shfl_xor(s, 32);
    colp[k] = s;
  }
  if (rw == 0) {
    #pragma unroll
    for (int k = 0; k < CPT; ++k) ldsp[w][c0 + k] = colp[k];
  }
  __syncthreads();
  if (t < DH) {
    float s = ldsp[0][t] + ldsp[1][t] + ldsp[2][t] + ldsp[3][t];
    atomicAdd(&cs[t], s);
    int i0 = blockIdx.x * 16;
    short8 o0, o1;
    #pragma unroll
    for (int r = 0; r < 8; ++r) o0[r] = (short)tile[r][t];
    #pragma unroll
    for (int r = 0; r < 8; ++r) o1[r] = (short)tile[8 + r][t];
    *(short8*)&hT[(size_t)t * NN + i0] = o0;
    *(short8*)&hT[(size_t)t * NN + i0 + 8] = o1;
  }
}

// ---------------- CSR build (once per launch; structure only) ----------------
__global__ void hist_kernel(const int* __restrict__ src, int* __restrict__ counts) {
  int e = blockIdx.x * 256 + threadIdx.x;
  atomicAdd(&counts[src[e]], 1);
}

__global__ __launch_bounds__(1024) void scan_kernel(const int* __restrict__ counts,
    int* __restrict__ offsets, int* __restrict__ cursor) {
  __shared__ int part[1024];
  int t = threadIdx.x;
  int v[4]; int run = 0;
  #pragma unroll
  for (int j = 0; j < 4; ++j) { v[j] = counts[4 * t + j]; run += v[j]; }
  part[t] = run;
  __syncthreads();
  for (int off = 1; off < 1024; off <<= 1) {
    int y = (t >= off) ? part[t - off] : 0;
    __syncthreads();
    part[t] += y;
    __syncthreads();
  }
  int base = part[t] - run;
  #pragma unroll
  for (int j = 0; j < 4; ++j) { offsets[4 * t + j] = base; cursor[4 * t + j] = base; base += v[j]; }
  if (t == 1023) offsets[NN] = base;
}

__global__ void scatter_idx_kernel(const int* __restrict__ src, const int* __restrict__ dst,
    int* __restrict__ cursor, int* __restrict__ dstS) {
  int e = blockIdx.x * 256 + threadIdx.x;
  int s = src[e];
  int p = atomicAdd(&cursor[s], 1);
  dstS[p] = dst[e];
}

// ---------------- fused edge branch: o = 0.5 * (sum_e e*h[d]) / (sum_e e) ----------------
template<int DH>
__global__ __launch_bounds__(256) void gather_kernel(const float* __restrict__ h,
    const int* __restrict__ offsets, const int* __restrict__ dstS,
    const float* __restrict__ al, const float* __restrict__ ar,
    const float* __restrict__ ab, float* __restrict__ o) {
  constexpr int VW = DH / 64;
  using V = typename std::conditional<VW == 4, f32x4, f32x2>::type;
  int wid = threadIdx.x >> 6, lane = threadIdx.x & 63;
  int i = blockIdx.x * 4 + wid;
  int beg = offsets[i], end = offsets[i + 1];
  float base = al[i] + ab[0];
  V acc0{}, acc1{};
  float esum0 = 0.f, esum1 = 0.f;
  int k = beg;
  for (; k + 2 <= end; k += 2) {
    int d0 = dstS[k], d1 = dstS[k + 1];
    float e0 = expf(lrelu_f(base + ar[d0]));
    float e1 = expf(lrelu_f(base + ar[d1]));
    V v0 = *(const V*)&h[(size_t)d0 * DH + lane * VW];
    V v1 = *(const V*)&h[(size_t)d1 * DH + lane * VW];
    esum0 += e0; esum1 += e1;
    acc0 += e0 * v0;
    acc1 += e1 * v1;
  }
  if (k < end) {
    int d0 = dstS[k];
    float e0 = expf(lrelu_f(base + ar[d0]));
    V v0 = *(const V*)&h[(size_t)d0 * DH + lane * VW];
    esum0 += e0;
    acc0 += e0 * v0;
  }
  float esum = esum0 + esum1;
  float rd = (beg < end) ? 0.5f / esum : 0.0f;
  *(V*)&o[(size_t)i * DH + lane * VW] = (acc0 + acc1) * rd;
}

// ---------------- Pass 1: QK^T (split bf16 MFMA) -> Delta weights W (bf16) + tile flags ----
// hi operands via LDS (double-buffered, 32KB total -> 4 blocks/CU); lo operands
// loaded straight from global into registers (L2-resident fragment loads).
// XCD-aware block swizzle: each XCD gets 4 contiguous bi-rows (bijective, nwg%8==0).
template<int DH>
__global__ __launch_bounds__(256) void qk_kernel(
    const u16* __restrict__ hhi, const u16* __restrict__ hlo,
    const float* __restrict__ al, const float* __restrict__ ar,
    const float* __restrict__ inv, const float* __restrict__ ab,
    u16* __restrict__ W, int* __restrict__ flags) {
  constexpr int KC = DH / 32;
  __shared__ u16 sA[2][128][32];   // [buf][row][col-swizzled] hi only, 16KB
  __shared__ u16 sB[2][128][32];   //                                    16KB
  // XCD swizzle (bijective): lin -> swz so XCD r owns bi in [4r, 4r+4)
  int lin = blockIdx.y * gridDim.x + blockIdx.x;
  int cpx = (gridDim.x * gridDim.y) >> 3;
  int swz = (lin & 7) * cpx + (lin >> 3);
  int bi = swz / gridDim.x, bj = swz % gridDim.x;
  int i0 = bi * 128;
  int j0 = bj * 128;
  int w = threadIdx.x >> 6, l = threadIdx.x & 63;
  int wr = w >> 1, wc = w & 1;
  int lr = l & 15, lk = l >> 4;

  int rl = l >> 2;
  int sc = ((l & 3) ^ ((l >> 3) & 3)) * 8;
  const u16* gAh0 = hhi + (size_t)(i0 + 32 * w + rl) * DH + sc;
  const u16* gBh0 = hhi + (size_t)(j0 + 32 * w + rl) * DH + sc;
  // per-lane fragment pointers for the lo terms (global -> register)
  const u16* pAl = hlo + (size_t)(i0 + 64 * wr + lr) * DH + lk * 8;
  const u16* pBl = hlo + (size_t)(j0 + 64 * wc + lr) * DH + lk * 8;

  f32x4 acc[4][4];
  #pragma unroll
  for (int q = 0; q < 4; ++q)
    #pragma unroll
    for (int s = 0; s < 4; ++s) acc[q][s] = (f32x4){0.f, 0.f, 0.f, 0.f};

#define QK_STAGE(buf, c) do { \
    gload_lds16(gAh0 + (c) * 32,           &sA[buf][32 * w][0]); \
    gload_lds16(gAh0 + 16 * DH + (c) * 32, &sA[buf][32 * w + 16][0]); \
    gload_lds16(gBh0 + (c) * 32,           &sB[buf][32 * w][0]); \
    gload_lds16(gBh0 + 16 * DH + (c) * 32, &sB[buf][32 * w + 16][0]); \
  } while (0)

  QK_STAGE(0, 0);
  __syncthreads();

  int cs = (lk ^ ((lr >> 1) & 3)) * 8;   // read-side swizzled chunk
  int cur = 0;
  for (int c = 0; c < KC; ++c) {
    if (c + 1 < KC) QK_STAGE(cur ^ 1, c + 1);
    // lo fragments straight from global (issue early; L2 hits)
    short8 Al[4], Bl[4];
    #pragma unroll
    for (int q = 0; q < 4; ++q) Al[q] = *(const short8*)(pAl + (size_t)(16 * q) * DH + c * 32);
    #pragma unroll
    for (int s = 0; s < 4; ++s) Bl[s] = *(const short8*)(pBl + (size_t)(16 * s) * DH + c * 32);
    short8 Ah[4], Bh[4];
    #pragma unroll
    for (int q = 0; q < 4; ++q)
      Ah[q] = *(const short8*)&sA[cur][64 * wr + 16 * q + lr][cs];
    #pragma unroll
    for (int s = 0; s < 4; ++s)
      Bh[s] = *(const short8*)&sB[cur][64 * wc + 16 * s + lr][cs];
    #pragma unroll
    for (int q = 0; q < 4; ++q)
      #pragma unroll
      for (int s = 0; s < 4; ++s) {
        acc[q][s] = __builtin_amdgcn_mfma_f32_16x16x32_bf16(Al[q], Bh[s], acc[q][s], 0, 0, 0);
        acc[q][s] = __builtin_amdgcn_mfma_f32_16x16x32_bf16(Ah[q], Bl[s], acc[q][s], 0, 0, 0);
        acc[q][s] = __builtin_amdgcn_mfma_f32_16x16x32_bf16(Ah[q], Bh[s], acc[q][s], 0, 0, 0);
      }
    __syncthreads();   // drains vmcnt (next chunk staged) + all reads of cur done
    cur ^= 1;
  }
#undef QK_STAGE

  float abv = ab[0];
  int i_base = i0 + 64 * wr + 4 * lk;   // + 16q + qq
  int j_base = j0 + 64 * wc + lr;       // + 16s
  float invj[4];
  #pragma unroll
  for (int s = 0; s < 4; ++s) invj[s] = inv[j_base + 16 * s];
  float invi16[16];
  #pragma unroll
  for (int q = 0; q < 4; ++q)
    #pragma unroll
    for (int qq = 0; qq < 4; ++qq) invi16[4 * q + qq] = inv[i_base + 16 * q + qq];

  // pass 1: cheap detection (no expm1)
  int wany = 0;
  #pragma unroll
  for (int q = 0; q < 4; ++q)
    #pragma unroll
    for (int s = 0; s < 4; ++s)
      #pragma unroll
      for (int qq = 0; qq < 4; ++qq) {
        float C = acc[q][s][qq] * invi16[4 * q + qq] * invj[s];
        if (C > 0.36f) wany = 1;
      }
  int anyv = __any(wany) ? 1 : 0;
  if (l == 0)
    flags[((i0 >> 6) + wr) * 64 + (j0 >> 6) + wc] = anyv;

  // pass 2: only active tiles compute expm1 and store W
  if (anyv) {
    float arj[4];
    #pragma unroll
    for (int s = 0; s < 4; ++s) arj[s] = ar[j_base + 16 * s] + abv;
    #pragma unroll
    for (int q = 0; q < 4; ++q) {
      float ali_[4];
      #pragma unroll
      for (int qq = 0; qq < 4; ++qq) ali_[qq] = al[i_base + 16 * q + qq];
      #pragma unroll
      for (int s = 0; s < 4; ++s)
        #pragma unroll
        for (int qq = 0; qq < 4; ++qq) {
          float C = acc[q][s][qq] * invi16[4 * q + qq] * invj[s];
          float wv = 0.0f;
          if (C > 0.36f) wv = expm1f(C * lrelu_f(ali_[qq] + arj[s]));
          W[(size_t)(i_base + 16 * q + qq) * NN + j_base + 16 * s] = f2bf(wv);
        }
    }
  }
}

// ---------------- Pass 2: o += h + 0.5*cs + 0.5*(W @ h), flag-gated ----------------
template<int DH>
__global__ __launch_bounds__(256) void pv_kernel(
    const u16* __restrict__ W, const u16* __restrict__ hT,
    const int* __restrict__ flags, const float* __restrict__ h,
    const float* __restrict__ cs, float* __restrict__ o) {
  __shared__ u16 sW[2][16][64];      // W tile: rows i0..i0+15, 64 j (swizzled cols)
  __shared__ u16 sT[2][4][16][64];   // per-wave hT tile: rows d0..d0+15, 64 j
  __shared__ int list[64];
  __shared__ int nact_s;
  int ib = blockIdx.x;
  int w = threadIdx.x >> 6, l = threadIdx.x & 63;
  int lr = l & 15, lk = l >> 4;
  int i0 = ib * 16;
  int d0 = blockIdx.y * 64 + w * 16;
  const int* frow = flags + (i0 >> 6) * 64;
  if (threadIdx.x < 64) {
    int f = frow[threadIdx.x] != 0;
    unsigned long long m = __ballot(f);
    int pos = __popcll(m & ((1ULL << threadIdx.x) - 1ULL));
    if (f) list[pos] = threadIdx.x;
    if (threadIdx.x == 0) nact_s = __popcll(m);
  }
  __syncthreads();
  int nact = nact_s;

  int srow0 = l >> 3;                      // row within 8-row group
  int scol = ((l & 7) * 8) ^ ((srow0 & 7) << 3);
  const u16* gW0 = W + (size_t)(i0 + srow0) * NN + scol;       // + 8*NN for rows 8..15
  const u16* gT0 = hT + (size_t)(d0 + srow0) * NN + scol;
  f32x4 acc0 = {0.f, 0.f, 0.f, 0.f};
  f32x4 acc1 = {0.f, 0.f, 0.f, 0.f};

  if (nact > 0) {
    {
      int j0 = list[0] * 64;
      if (w == 0) {
        gload_lds16(gW0 + j0, &sW[0][0][0]);
        gload_lds16(gW0 + 8 * NN + j0, &sW[0][8][0]);
      }
      gload_lds16(gT0 + j0, &sT[0][w][0][0]);
      gload_lds16(gT0 + 8 * NN + j0, &sT[0][w][8][0]);
    }
    __syncthreads();
    int cur = 0;
    for (int t = 0; t < nact; ++t) {
      if (t + 1 < nact) {
        int jn = list[t + 1] * 64;
        int nb = cur ^ 1;
        if (w == 0) {
          gload_lds16(gW0 + jn, &sW[nb][0][0]);
          gload_lds16(gW0 + 8 * NN + jn, &sW[nb][8][0]);
        }
        gload_lds16(gT0 + jn, &sT[nb][w][0][0]);
        gload_lds16(gT0 + 8 * NN + jn, &sT[nb][w][8][0]);
      }
      int sx = (lr & 7) << 3;                    // read-side XOR for row lr
      short8 a0 = *(const short8*)&sW[cur][lr][(lk * 8) ^ sx];
      short8 a1 = *(const short8*)&sW[cur][lr][(32 + lk * 8) ^ sx];
      short8 b0 = *(const short8*)&sT[cur][w][lr][(lk * 8) ^ sx];
      short8 b1 = *(const short8*)&sT[cur][w][lr][(32 + lk * 8) ^ sx];
      acc0 = __builtin_amdgcn_mfma_f32_16x16x32_bf16(a0, b0, acc0, 0, 0, 0);
      acc1 = __builtin_amdgcn_mfma_f32_16x16x32_bf16(a1, b1, acc1, 0, 0, 0);
      __syncthreads();   // drains vmcnt (next tile staged) + all reads of cur done
      cur ^= 1;
    }
  }

  int d = d0 + lr;
  #pragma unroll
  for (int q = 0; q < 4; ++q) {
    int i = i0 + 4 * lk + q;
    size_t idx = (size_t)i * DH + d;
    o[idx] = o[idx] + h[idx] + 0.5f * cs[d] + 0.5f * (acc0[q] + acc1[q]);
  }
}

// ---------------- host-side orchestration ----------------
struct Scratch {
  float *al, *ar, *inv, *cs1, *cs2;
  int *counts, *offsets, *cursor, *dstS, *flags;
  u16 *hhi, *hlo, *hT, *W;
  u16 *w1h, *w1l, *w2h, *w2l, *w3h, *w3l;
};

template<int DH>
static void run_attention(const float* h, const float* aw, const float* ab, float* o,
                          float* cs, const Scratch& S, hipStream_t stream) {
  prep_kernel<DH><<<NN / 16, 256, 0, stream>>>(h, aw, S.al, S.ar, S.inv, cs,
                                               S.hhi, S.hlo, S.hT);
  gather_kernel<DH><<<NN / 4, 256, 0, stream>>>(h, S.offsets, S.dstS, S.al, S.ar, ab, o);
  qk_kernel<DH><<<dim3(NN / 128, NN / 128), 256, 0, stream>>>(
      S.hhi, S.hlo, S.al, S.ar, S.inv, ab, S.W, S.flags);
  pv_kernel<DH><<<dim3(NN / 16, DH / 64), 256, 0, stream>>>(
      S.W, S.hT, S.flags, h, cs, o);
}

extern "C" void kernel_launch(void* const* d_in, const int* in_sizes, int n_in,
                              void* d_out, int out_size, void* d_ws, size_t ws_size,
                              hipStream_t stream) {
  const float* X   = (const float*)d_in[0];
  const int*   ei  = (const int*)d_in[1];
  const float* W1  = (const float*)d_in[2];
  const float* b1  = (const float*)d_in[3];
  const float* a1w = (const float*)d_in[4];
  const float* a1b = (const float*)d_in[5];
  const float* W2  = (const float*)d_in[6];
  const float* b2  = (const float*)d_in[7];
  const float* a2w = (const float*)d_in[8];
  const float* a2b = (const float*)d_in[9];
  const float* W3  = (const float*)d_in[10];
  const float* b3  = (const float*)d_in[11];
  float* out = (float*)d_out;

  const int* src = ei;
  const int* dst = ei + NE;

  char* p = (char*)d_ws;
  auto alloc = [&](size_t bytes) { char* r = p; p += (bytes + 255) & ~(size_t)255; return r; };
  float* h1 = (float*)alloc((size_t)NN * 256 * 4);
  float* o1 = (float*)alloc((size_t)NN * 256 * 4);
  float* h2 = (float*)alloc((size_t)NN * 128 * 4);
  float* o2 = (float*)alloc((size_t)NN * 128 * 4);
  Scratch S;
  S.counts = (int*)alloc(NN * 4);
  S.cs1    = (float*)alloc(256 * 4);
  S.cs2    = (float*)alloc(128 * 4);
  S.hhi = (u16*)alloc((size_t)NN * 256 * 2);
  S.hlo = (u16*)alloc((size_t)NN * 256 * 2);
  S.hT  = (u16*)alloc((size_t)NN * 256 * 2);
  S.W   = (u16*)alloc((size_t)NN * NN * 2);
  S.w1h = (u16*)alloc((size_t)256 * 128 * 2);
  S.w1l = (u16*)alloc((size_t)256 * 128 * 2);
  S.w2h = (u16*)alloc((size_t)128 * 256 * 2);
  S.w2l = (u16*)alloc((size_t)128 * 256 * 2);
  S.w3h = (u16*)alloc((size_t)64 * 128 * 2);
  S.w3l = (u16*)alloc((size_t)64 * 128 * 2);
  S.flags = (int*)alloc(4096 * 4);
  S.al    = (float*)alloc(NN * 4);
  S.ar    = (float*)alloc(NN * 4);
  S.inv   = (float*)alloc(NN * 4);
  S.offsets = (int*)alloc((NN + 1) * 4);
  S.cursor  = (int*)alloc(NN * 4);
  S.dstS    = (int*)alloc((size_t)NE * 4);

  hipMemsetAsync(S.counts, 0, NN * 4 + 256 * 4 + 128 * 4, stream);
  hist_kernel<<<NE / 256, 256, 0, stream>>>(src, S.counts);
  scan_kernel<<<1, 1024, 0, stream>>>(S.counts, S.offsets, S.cursor);
  scatter_idx_kernel<<<NE / 256, 256, 0, stream>>>(src, dst, S.cursor, S.dstS);
  wtrans_all_kernel<<<72, 256, 0, stream>>>(W1, W2, W3,
      S.w1h, S.w1l, S.w2h, S.w2l, S.w3h, S.w3l);

  // ---- layer 1: h1 = X @ W1 + b1 ----
  mgemm_kernel<128, 256, false, false><<<dim3(NN / 16, 256 / 64), 256, 0, stream>>>(
      X, S.w1h, S.w1l, b1, h1);
  run_attention<256>(h1, a1w, a1b, o1, S.cs1, S, stream);

  // ---- layer 2: h2 = relu(o1) @ W2 + b2 ----
  mgemm_kernel<256, 128, true, false><<<dim3(NN / 16, 128 / 64), 256, 0, stream>>>(
      o1, S.w2h, S.w2l, b2, h2);
  run_attention<128>(h2, a2w, a2b, o2, S.cs2, S, stream);

  // ---- output layer: out = normalize(relu(o2) @ W3 + b3) ----
  mgemm_kernel<128, 64, true, true><<<dim3(NN / 16, 64 / 64), 256, 0, stream>>>(
      o2, S.w3h, S.w3l, b3, out);
}

// Round 18
// 243.585 us; speedup vs baseline: 1.1202x; 1.1202x over previous
//
#include <hip/hip_runtime.h>
#include <math.h>
#include <type_traits>

#define NN 4096
#define NE 131072

typedef short short8 __attribute__((ext_vector_type(8)));
typedef float f32x4 __attribute__((ext_vector_type(4)));
typedef float f32x2 __attribute__((ext_vector_type(2)));
typedef unsigned short u16;

__device__ __forceinline__ float lrelu_f(float x) { return x > 0.0f ? x : 0.01f * x; }

__device__ __forceinline__ u16 f2bf(float x) {
  unsigned int u = __float_as_uint(x);
  unsigned int r = (u + 0x7FFF + ((u >> 16) & 1)) >> 16;   // RNE
  return (u16)r;
}
__device__ __forceinline__ float bf2f(u16 b) { return __uint_as_float(((unsigned int)b) << 16); }

__device__ __forceinline__ void gload_lds16(const u16* g, u16* l) {
  __builtin_amdgcn_global_load_lds((const __attribute__((address_space(1))) void*)g,
                                   (__attribute__((address_space(3))) void*)l, 16, 0, 0);
}

// ---------------- batched weight transpose+split (all 3 layers, one launch) ----------------
__global__ __launch_bounds__(256) void wtrans_all_kernel(
    const float* __restrict__ W1, const float* __restrict__ W2, const float* __restrict__ W3,
    u16* __restrict__ w1h, u16* __restrict__ w1l,
    u16* __restrict__ w2h, u16* __restrict__ w2l,
    u16* __restrict__ w3h, u16* __restrict__ w3l) {
  __shared__ u16 th[32][33], tl[32][33];
  const float* W; u16 *oh, *ol; int K, P, bp, bk;
  int bx = blockIdx.x;
  if (bx < 32)      { W = W1; oh = w1h; ol = w1l; K = 128; P = 256; int b = bx;      bp = b & 7; bk = b >> 3; }
  else if (bx < 64) { W = W2; oh = w2h; ol = w2l; K = 256; P = 128; int b = bx - 32; bp = b & 3; bk = b >> 2; }
  else              { W = W3; oh = w3h; ol = w3l; K = 128; P = 64;  int b = bx - 64; bp = b & 1; bk = b >> 1; }
  int t = threadIdx.x, tx = t & 31, ty8 = t >> 5;
  #pragma unroll
  for (int r = 0; r < 4; ++r) {
    int k = bk * 32 + ty8 + r * 8;
    int p = bp * 32 + tx;
    float x = W[(size_t)k * P + p];
    u16 hi = f2bf(x);
    th[ty8 + r * 8][tx] = hi;
    tl[ty8 + r * 8][tx] = f2bf(x - bf2f(hi));
  }
  __syncthreads();
  #pragma unroll
  for (int r = 0; r < 4; ++r) {
    int p = bp * 32 + ty8 + r * 8;
    int k = bk * 32 + tx;
    oh[(size_t)p * K + k] = th[tx][ty8 + r * 8];
    ol[(size_t)p * K + k] = tl[tx][ty8 + r * 8];
  }
}

// ---------------- MFMA GEMM: O = act(A fp32) @ WT^T + bias; optional fused row-normalize ----
template<int K, int P, bool RELU, bool NORM>
__global__ __launch_bounds__(256) void mgemm_kernel(
    const float* __restrict__ A,
    const u16* __restrict__ WThi, const u16* __restrict__ WTlo,
    const float* __restrict__ bias, float* __restrict__ O) {
  constexpr int KC = K / 32;
  __shared__ float ldsn[4][16];
  int w = threadIdx.x >> 6, l = threadIdx.x & 63;
  int lr = l & 15, lk = l >> 4;
  int i0 = blockIdx.x * 16;
  int p0 = blockIdx.y * 64 + w * 16;
  const float* ar_ = A + (size_t)(i0 + lr) * K + lk * 8;
  const u16* brh = WThi + (size_t)(p0 + lr) * K + lk * 8;
  const u16* brl = WTlo + (size_t)(p0 + lr) * K + lk * 8;
  f32x4 ahh = {0.f, 0.f, 0.f, 0.f};
  f32x4 ahl = {0.f, 0.f, 0.f, 0.f};
  f32x4 alh = {0.f, 0.f, 0.f, 0.f};
  #pragma unroll
  for (int c = 0; c < KC; ++c) {
    f32x4 a0 = *(const f32x4*)(ar_ + 32 * c);
    f32x4 a1 = *(const f32x4*)(ar_ + 32 * c + 4);
    float av[8] = {a0[0], a0[1], a0[2], a0[3], a1[0], a1[1], a1[2], a1[3]};
    short8 Ah, Al;
    #pragma unroll
    for (int j = 0; j < 8; ++j) {
      float x = av[j];
      if (RELU) x = fmaxf(x, 0.0f);
      u16 hi = f2bf(x);
      Ah[j] = (short)hi;
      Al[j] = (short)f2bf(x - bf2f(hi));
    }
    short8 Bh = *(const short8*)(brh + 32 * c);
    short8 Bl = *(const short8*)(brl + 32 * c);
    ahh = __builtin_amdgcn_mfma_f32_16x16x32_bf16(Ah, Bh, ahh, 0, 0, 0);
    ahl = __builtin_amdgcn_mfma_f32_16x16x32_bf16(Ah, Bl, ahl, 0, 0, 0);
    alh = __builtin_amdgcn_mfma_f32_16x16x32_bf16(Al, Bh, alh, 0, 0, 0);
  }
  int p = p0 + lr;
  float bv = bias[p];
  float ov[4];
  #pragma unroll
  for (int q = 0; q < 4; ++q) ov[q] = ahh[q] + ahl[q] + alh[q] + bv;

  if (NORM) {
    float sq[4];
    #pragma unroll
    for (int q = 0; q < 4; ++q) {
      float s = ov[q] * ov[q];
      #pragma unroll
      for (int m = 1; m < 16; m <<= 1) s += __shfl_xor(s, m);
      sq[q] = s;
    }
    if (lr == 0) {
      #pragma unroll
      for (int q = 0; q < 4; ++q) ldsn[w][4 * lk + q] = sq[q];
    }
    __syncthreads();
    #pragma unroll
    for (int q = 0; q < 4; ++q) {
      int row = 4 * lk + q;
      float n2 = ldsn[0][row] + ldsn[1][row] + ldsn[2][row] + ldsn[3][row];
      float nf = 1.0f / fmaxf(sqrtf(n2), 1e-12f);
      int i = i0 + row;
      O[(size_t)i * P + p] = ov[q] * nf;
    }
  } else {
    #pragma unroll
    for (int q = 0; q < 4; ++q) {
      int i = i0 + 4 * lk + q;
      O[(size_t)i * P + p] = ov[q];
    }
  }
}

// ---------------- fused prep: rowstats + colsum + bf16 split + transpose ----------------
template<int DH>
__global__ __launch_bounds__(256) void prep_kernel(const float* __restrict__ h,
    const float* __restrict__ aw, float* __restrict__ al, float* __restrict__ ar,
    float* __restrict__ inv, float* __restrict__ cs,
    u16* __restrict__ hhi, u16* __restrict__ hlo, u16* __restrict__ hT) {
  constexpr int CPT = DH / 16;
  __shared__ u16 tile[16][DH + 8];
  __shared__ float ldsp[4][DH];
  int t = threadIdx.x;
  int w = t >> 6, l = t & 63;
  int rw = l >> 4;
  int row = w * 4 + rw;
  int tcol = l & 15;
  int i = blockIdx.x * 16 + row;
  int c0 = tcol * CPT;

  float v[CPT];
  const float* hr = h + (size_t)i * DH + c0;
  #pragma unroll
  for (int k = 0; k < CPT; k += 4) {
    f32x4 x = *(const f32x4*)(hr + k);
    v[k] = x[0]; v[k + 1] = x[1]; v[k + 2] = x[2]; v[k + 3] = x[3];
  }
  float s2 = 0.f, sl = 0.f, sr = 0.f;
  #pragma unroll
  for (int k = 0; k < CPT; ++k) {
    s2 = fmaf(v[k], v[k], s2);
    sl = fmaf(v[k], aw[c0 + k], sl);
    sr = fmaf(v[k], aw[DH + c0 + k], sr);
  }
  #pragma unroll
  for (int m = 1; m < 16; m <<= 1) {
    s2 += __shfl_xor(s2, m);
    sl += __shfl_xor(sl, m);
    sr += __shfl_xor(sr, m);
  }
  if (tcol == 0) { al[i] = sl; ar[i] = sr; inv[i] = rsqrtf(s2); }

  short8 hs[CPT / 8], ls[CPT / 8];
  #pragma unroll
  for (int k = 0; k < CPT; ++k) {
    float x = v[k];
    u16 hi = f2bf(x);
    hs[k / 8][k & 7] = (short)hi;
    ls[k / 8][k & 7] = (short)f2bf(x - bf2f(hi));
  }
  #pragma unroll
  for (int b = 0; b < CPT / 8; ++b) {
    *(short8*)&hhi[(size_t)i * DH + c0 + b * 8] = hs[b];
    *(short8*)&hlo[(size_t)i * DH + c0 + b * 8] = ls[b];
    *(short8*)&tile[row][c0 + b * 8] = hs[b];
  }
  float colp[CPT];
  #pragma unroll
  for (int k = 0; k < CPT; ++k) {
    float s = v[k];
    s += __shfl_xor(s, 16);
    s += __shfl_xor(s, 32);
    colp[k] = s;
  }
  if (rw == 0) {
    #pragma unroll
    for (int k = 0; k < CPT; ++k) ldsp[w][c0 + k] = colp[k];
  }
  __syncthreads();
  if (t < DH) {
    float s = ldsp[0][t] + ldsp[1][t] + ldsp[2][t] + ldsp[3][t];
    atomicAdd(&cs[t], s);
    int i0 = blockIdx.x * 16;
    short8 o0, o1;
    #pragma unroll
    for (int r = 0; r < 8; ++r) o0[r] = (short)tile[r][t];
    #pragma unroll
    for (int r = 0; r < 8; ++r) o1[r] = (short)tile[8 + r][t];
    *(short8*)&hT[(size_t)t * NN + i0] = o0;
    *(short8*)&hT[(size_t)t * NN + i0 + 8] = o1;
  }
}

// ---------------- CSR build (once per launch; structure only) ----------------
__global__ void hist_kernel(const int* __restrict__ src, int* __restrict__ counts) {
  int e = blockIdx.x * 256 + threadIdx.x;
  atomicAdd(&counts[src[e]], 1);
}

__global__ __launch_bounds__(1024) void scan_kernel(const int* __restrict__ counts,
    int* __restrict__ offsets, int* __restrict__ cursor) {
  __shared__ int part[1024];
  int t = threadIdx.x;
  int v[4]; int run = 0;
  #pragma unroll
  for (int j = 0; j < 4; ++j) { v[j] = counts[4 * t + j]; run += v[j]; }
  part[t] = run;
  __syncthreads();
  for (int off = 1; off < 1024; off <<= 1) {
    int y = (t >= off) ? part[t - off] : 0;
    __syncthreads();
    part[t] += y;
    __syncthreads();
  }
  int base = part[t] - run;
  #pragma unroll
  for (int j = 0; j < 4; ++j) { offsets[4 * t + j] = base; cursor[4 * t + j] = base; base += v[j]; }
  if (t == 1023) offsets[NN] = base;
}

__global__ void scatter_idx_kernel(const int* __restrict__ src, const int* __restrict__ dst,
    int* __restrict__ cursor, int* __restrict__ dstS) {
  int e = blockIdx.x * 256 + threadIdx.x;
  int s = src[e];
  int p = atomicAdd(&cursor[s], 1);
  dstS[p] = dst[e];
}

// ---------------- fused edge branch: o = 0.5 * (sum_e e*h[d]) / (sum_e e) ----------------
// 4-edge unroll: 4 independent acc/esum chains -> 4 row fetches in flight.
template<int DH>
__global__ __launch_bounds__(256) void gather_kernel(const float* __restrict__ h,
    const int* __restrict__ offsets, const int* __restrict__ dstS,
    const float* __restrict__ al, const float* __restrict__ ar,
    const float* __restrict__ ab, float* __restrict__ o) {
  constexpr int VW = DH / 64;
  using V = typename std::conditional<VW == 4, f32x4, f32x2>::type;
  int wid = threadIdx.x >> 6, lane = threadIdx.x & 63;
  int i = blockIdx.x * 4 + wid;
  int beg = offsets[i], end = offsets[i + 1];
  float base = al[i] + ab[0];
  V acc0{}, acc1{}, acc2{}, acc3{};
  float esum0 = 0.f, esum1 = 0.f, esum2 = 0.f, esum3 = 0.f;
  int k = beg;
  for (; k + 4 <= end; k += 4) {
    int d0 = dstS[k], d1 = dstS[k + 1], d2 = dstS[k + 2], d3 = dstS[k + 3];
    float e0 = expf(lrelu_f(base + ar[d0]));
    float e1 = expf(lrelu_f(base + ar[d1]));
    float e2 = expf(lrelu_f(base + ar[d2]));
    float e3 = expf(lrelu_f(base + ar[d3]));
    V v0 = *(const V*)&h[(size_t)d0 * DH + lane * VW];
    V v1 = *(const V*)&h[(size_t)d1 * DH + lane * VW];
    V v2 = *(const V*)&h[(size_t)d2 * DH + lane * VW];
    V v3 = *(const V*)&h[(size_t)d3 * DH + lane * VW];
    esum0 += e0; esum1 += e1; esum2 += e2; esum3 += e3;
    acc0 += e0 * v0;
    acc1 += e1 * v1;
    acc2 += e2 * v2;
    acc3 += e3 * v3;
  }
  for (; k < end; ++k) {
    int d0 = dstS[k];
    float e0 = expf(lrelu_f(base + ar[d0]));
    V v0 = *(const V*)&h[(size_t)d0 * DH + lane * VW];
    esum0 += e0;
    acc0 += e0 * v0;
  }
  float esum = (esum0 + esum1) + (esum2 + esum3);
  float rd = (beg < end) ? 0.5f / esum : 0.0f;
  *(V*)&o[(size_t)i * DH + lane * VW] = ((acc0 + acc1) + (acc2 + acc3)) * rd;
}

// ---------------- Pass 1: QK^T (split bf16 MFMA) -> Delta weights W (bf16) + tile flags ----
// (round-14 proven structure: full hi/lo LDS staging, 64KB, single-pass epilogue)
template<int DH>
__global__ __launch_bounds__(256) void qk_kernel(
    const u16* __restrict__ hhi, const u16* __restrict__ hlo,
    const float* __restrict__ al, const float* __restrict__ ar,
    const float* __restrict__ inv, const float* __restrict__ ab,
    u16* __restrict__ W, int* __restrict__ flags) {
  constexpr int KC = DH / 32;
  __shared__ u16 sA[2][2][128][32];   // [buf][hi/lo][row][col-swizzled]  32KB
  __shared__ u16 sB[2][2][128][32];   //                                   32KB
  int i0 = blockIdx.x * 128;
  int j0 = blockIdx.y * 128;
  int w = threadIdx.x >> 6, l = threadIdx.x & 63;
  int wr = w >> 1, wc = w & 1;
  int lr = l & 15, lk = l >> 4;

  int rl = l >> 2;
  int sc = ((l & 3) ^ ((l >> 3) & 3)) * 8;
  const u16* gAh0 = hhi + (size_t)(i0 + 32 * w + rl) * DH + sc;
  const u16* gAl0 = hlo + (size_t)(i0 + 32 * w + rl) * DH + sc;
  const u16* gBh0 = hhi + (size_t)(j0 + 32 * w + rl) * DH + sc;
  const u16* gBl0 = hlo + (size_t)(j0 + 32 * w + rl) * DH + sc;

  f32x4 acc[4][4];
  #pragma unroll
  for (int q = 0; q < 4; ++q)
    #pragma unroll
    for (int s = 0; s < 4; ++s) acc[q][s] = (f32x4){0.f, 0.f, 0.f, 0.f};

#define QK_STAGE(buf, c) do { \
    gload_lds16(gAh0 + (c) * 32,           &sA[buf][0][32 * w][0]); \
    gload_lds16(gAh0 + 16 * DH + (c) * 32, &sA[buf][0][32 * w + 16][0]); \
    gload_lds16(gAl0 + (c) * 32,           &sA[buf][1][32 * w][0]); \
    gload_lds16(gAl0 + 16 * DH + (c) * 32, &sA[buf][1][32 * w + 16][0]); \
    gload_lds16(gBh0 + (c) * 32,           &sB[buf][0][32 * w][0]); \
    gload_lds16(gBh0 + 16 * DH + (c) * 32, &sB[buf][0][32 * w + 16][0]); \
    gload_lds16(gBl0 + (c) * 32,           &sB[buf][1][32 * w][0]); \
    gload_lds16(gBl0 + 16 * DH + (c) * 32, &sB[buf][1][32 * w + 16][0]); \
  } while (0)

  QK_STAGE(0, 0);
  __syncthreads();

  int cs = (lk ^ ((lr >> 1) & 3)) * 8;   // read-side swizzled chunk
  int cur = 0;
  for (int c = 0; c < KC; ++c) {
    if (c + 1 < KC) QK_STAGE(cur ^ 1, c + 1);
    short8 Ah[4], Al[4], Bh[4], Bl[4];
    #pragma unroll
    for (int q = 0; q < 4; ++q) {
      Ah[q] = *(const short8*)&sA[cur][0][64 * wr + 16 * q + lr][cs];
      Al[q] = *(const short8*)&sA[cur][1][64 * wr + 16 * q + lr][cs];
    }
    #pragma unroll
    for (int s = 0; s < 4; ++s) {
      Bh[s] = *(const short8*)&sB[cur][0][64 * wc + 16 * s + lr][cs];
      Bl[s] = *(const short8*)&sB[cur][1][64 * wc + 16 * s + lr][cs];
    }
    #pragma unroll
    for (int q = 0; q < 4; ++q)
      #pragma unroll
      for (int s = 0; s < 4; ++s) {
        acc[q][s] = __builtin_amdgcn_mfma_f32_16x16x32_bf16(Al[q], Bh[s], acc[q][s], 0, 0, 0);
        acc[q][s] = __builtin_amdgcn_mfma_f32_16x16x32_bf16(Ah[q], Bl[s], acc[q][s], 0, 0, 0);
        acc[q][s] = __builtin_amdgcn_mfma_f32_16x16x32_bf16(Ah[q], Bh[s], acc[q][s], 0, 0, 0);
      }
    __syncthreads();   // drains vmcnt (next chunk staged) + all reads of cur done
    cur ^= 1;
  }
#undef QK_STAGE

  float abv = ab[0];
  int i_base = i0 + 64 * wr + 4 * lk;   // + 16q + qq
  int j_base = j0 + 64 * wc + lr;       // + 16s
  float arj[4], invj[4];
  #pragma unroll
  for (int s = 0; s < 4; ++s) {
    int j = j_base + 16 * s;
    arj[s] = ar[j] + abv;
    invj[s] = inv[j];
  }
  int wany = 0;
  #pragma unroll
  for (int q = 0; q < 4; ++q) {
    float ali_[4], invi_[4];
    #pragma unroll
    for (int qq = 0; qq < 4; ++qq) {
      int i = i_base + 16 * q + qq;
      ali_[qq] = al[i];
      invi_[qq] = inv[i];
    }
    #pragma unroll
    for (int s = 0; s < 4; ++s)
      #pragma unroll
      for (int qq = 0; qq < 4; ++qq) {
        float C = acc[q][s][qq] * invi_[qq] * invj[s];
        float wv = 0.0f;
        if (C > 0.36f) wv = expm1f(C * lrelu_f(ali_[qq] + arj[s]));
        if (wv != 0.0f) wany = 1;
        W[(size_t)(i_base + 16 * q + qq) * NN + j_base + 16 * s] = f2bf(wv);
      }
  }
  int anyv = __any(wany) ? 1 : 0;
  if (l == 0)
    flags[((i0 >> 6) + wr) * 64 + (j0 >> 6) + wc] = anyv;
}

// ---------------- Pass 2: o += h + 0.5*cs + 0.5*(W @ h), flag-gated ----------------
template<int DH>
__global__ __launch_bounds__(256) void pv_kernel(
    const u16* __restrict__ W, const u16* __restrict__ hT,
    const int* __restrict__ flags, const float* __restrict__ h,
    const float* __restrict__ cs, float* __restrict__ o) {
  __shared__ u16 sW[2][16][64];      // W tile: rows i0..i0+15, 64 j (swizzled cols)
  __shared__ u16 sT[2][4][16][64];   // per-wave hT tile: rows d0..d0+15, 64 j
  __shared__ int list[64];
  __shared__ int nact_s;
  int ib = blockIdx.x;
  int w = threadIdx.x >> 6, l = threadIdx.x & 63;
  int lr = l & 15, lk = l >> 4;
  int i0 = ib * 16;
  int d0 = blockIdx.y * 64 + w * 16;
  const int* frow = flags + (i0 >> 6) * 64;
  if (threadIdx.x < 64) {
    int f = frow[threadIdx.x] != 0;
    unsigned long long m = __ballot(f);
    int pos = __popcll(m & ((1ULL << threadIdx.x) - 1ULL));
    if (f) list[pos] = threadIdx.x;
    if (threadIdx.x == 0) nact_s = __popcll(m);
  }
  __syncthreads();
  int nact = nact_s;

  int srow0 = l >> 3;                      // row within 8-row group
  int scol = ((l & 7) * 8) ^ ((srow0 & 7) << 3);
  const u16* gW0 = W + (size_t)(i0 + srow0) * NN + scol;       // + 8*NN for rows 8..15
  const u16* gT0 = hT + (size_t)(d0 + srow0) * NN + scol;
  f32x4 acc0 = {0.f, 0.f, 0.f, 0.f};
  f32x4 acc1 = {0.f, 0.f, 0.f, 0.f};

  if (nact > 0) {
    {
      int j0 = list[0] * 64;
      if (w == 0) {
        gload_lds16(gW0 + j0, &sW[0][0][0]);
        gload_lds16(gW0 + 8 * NN + j0, &sW[0][8][0]);
      }
      gload_lds16(gT0 + j0, &sT[0][w][0][0]);
      gload_lds16(gT0 + 8 * NN + j0, &sT[0][w][8][0]);
    }
    __syncthreads();
    int cur = 0;
    for (int t = 0; t < nact; ++t) {
      if (t + 1 < nact) {
        int jn = list[t + 1] * 64;
        int nb = cur ^ 1;
        if (w == 0) {
          gload_lds16(gW0 + jn, &sW[nb][0][0]);
          gload_lds16(gW0 + 8 * NN + jn, &sW[nb][8][0]);
        }
        gload_lds16(gT0 + jn, &sT[nb][w][0][0]);
        gload_lds16(gT0 + 8 * NN + jn, &sT[nb][w][8][0]);
      }
      int sx = (lr & 7) << 3;                    // read-side XOR for row lr
      short8 a0 = *(const short8*)&sW[cur][lr][(lk * 8) ^ sx];
      short8 a1 = *(const short8*)&sW[cur][lr][(32 + lk * 8) ^ sx];
      short8 b0 = *(const short8*)&sT[cur][w][lr][(lk * 8) ^ sx];
      short8 b1 = *(const short8*)&sT[cur][w][lr][(32 + lk * 8) ^ sx];
      acc0 = __builtin_amdgcn_mfma_f32_16x16x32_bf16(a0, b0, acc0, 0, 0, 0);
      acc1 = __builtin_amdgcn_mfma_f32_16x16x32_bf16(a1, b1, acc1, 0, 0, 0);
      __syncthreads();   // drains vmcnt (next tile staged) + all reads of cur done
      cur ^= 1;
    }
  }

  int d = d0 + lr;
  #pragma unroll
  for (int q = 0; q < 4; ++q) {
    int i = i0 + 4 * lk + q;
    size_t idx = (size_t)i * DH + d;
    o[idx] = o[idx] + h[idx] + 0.5f * cs[d] + 0.5f * (acc0[q] + acc1[q]);
  }
}

// ---------------- host-side orchestration ----------------
struct Scratch {
  float *al, *ar, *inv, *cs1, *cs2;
  int *counts, *offsets, *cursor, *dstS, *flags;
  u16 *hhi, *hlo, *hT, *W;
  u16 *w1h, *w1l, *w2h, *w2l, *w3h, *w3l;
};

template<int DH>
static void run_attention(const float* h, const float* aw, const float* ab, float* o,
                          float* cs, const Scratch& S, hipStream_t stream) {
  prep_kernel<DH><<<NN / 16, 256, 0, stream>>>(h, aw, S.al, S.ar, S.inv, cs,
                                               S.hhi, S.hlo, S.hT);
  gather_kernel<DH><<<NN / 4, 256, 0, stream>>>(h, S.offsets, S.dstS, S.al, S.ar, ab, o);
  qk_kernel<DH><<<dim3(NN / 128, NN / 128), 256, 0, stream>>>(
      S.hhi, S.hlo, S.al, S.ar, S.inv, ab, S.W, S.flags);
  pv_kernel<DH><<<dim3(NN / 16, DH / 64), 256, 0, stream>>>(
      S.W, S.hT, S.flags, h, cs, o);
}

extern "C" void kernel_launch(void* const* d_in, const int* in_sizes, int n_in,
                              void* d_out, int out_size, void* d_ws, size_t ws_size,
                              hipStream_t stream) {
  const float* X   = (const float*)d_in[0];
  const int*   ei  = (const int*)d_in[1];
  const float* W1  = (const float*)d_in[2];
  const float* b1  = (const float*)d_in[3];
  const float* a1w = (const float*)d_in[4];
  const float* a1b = (const float*)d_in[5];
  const float* W2  = (const float*)d_in[6];
  const float* b2  = (const float*)d_in[7];
  const float* a2w = (const float*)d_in[8];
  const float* a2b = (const float*)d_in[9];
  const float* W3  = (const float*)d_in[10];
  const float* b3  = (const float*)d_in[11];
  float* out = (float*)d_out;

  const int* src = ei;
  const int* dst = ei + NE;

  char* p = (char*)d_ws;
  auto alloc = [&](size_t bytes) { char* r = p; p += (bytes + 255) & ~(size_t)255; return r; };
  float* h1 = (float*)alloc((size_t)NN * 256 * 4);
  float* o1 = (float*)alloc((size_t)NN * 256 * 4);
  float* h2 = (float*)alloc((size_t)NN * 128 * 4);
  float* o2 = (float*)alloc((size_t)NN * 128 * 4);
  Scratch S;
  S.counts = (int*)alloc(NN * 4);
  S.cs1    = (float*)alloc(256 * 4);
  S.cs2    = (float*)alloc(128 * 4);
  S.hhi = (u16*)alloc((size_t)NN * 256 * 2);
  S.hlo = (u16*)alloc((size_t)NN * 256 * 2);
  S.hT  = (u16*)alloc((size_t)NN * 256 * 2);
  S.W   = (u16*)alloc((size_t)NN * NN * 2);
  S.w1h = (u16*)alloc((size_t)256 * 128 * 2);
  S.w1l = (u16*)alloc((size_t)256 * 128 * 2);
  S.w2h = (u16*)alloc((size_t)128 * 256 * 2);
  S.w2l = (u16*)alloc((size_t)128 * 256 * 2);
  S.w3h = (u16*)alloc((size_t)64 * 128 * 2);
  S.w3l = (u16*)alloc((size_t)64 * 128 * 2);
  S.flags = (int*)alloc(4096 * 4);
  S.al    = (float*)alloc(NN * 4);
  S.ar    = (float*)alloc(NN * 4);
  S.inv   = (float*)alloc(NN * 4);
  S.offsets = (int*)alloc((NN + 1) * 4);
  S.cursor  = (int*)alloc(NN * 4);
  S.dstS    = (int*)alloc((size_t)NE * 4);

  hipMemsetAsync(S.counts, 0, NN * 4 + 256 * 4 + 128 * 4, stream);
  hist_kernel<<<NE / 256, 256, 0, stream>>>(src, S.counts);
  scan_kernel<<<1, 1024, 0, stream>>>(S.counts, S.offsets, S.cursor);
  scatter_idx_kernel<<<NE / 256, 256, 0, stream>>>(src, dst, S.cursor, S.dstS);
  wtrans_all_kernel<<<72, 256, 0, stream>>>(W1, W2, W3,
      S.w1h, S.w1l, S.w2h, S.w2l, S.w3h, S.w3l);

  // ---- layer 1: h1 = X @ W1 + b1 ----
  mgemm_kernel<128, 256, false, false><<<dim3(NN / 16, 256 / 64), 256, 0, stream>>>(
      X, S.w1h, S.w1l, b1, h1);
  run_attention<256>(h1, a1w, a1b, o1, S.cs1, S, stream);

  // ---- layer 2: h2 = relu(o1) @ W2 + b2 ----
  mgemm_kernel<256, 128, true, false><<<dim3(NN / 16, 128 / 64), 256, 0, stream>>>(
      o1, S.w2h, S.w2l, b2, h2);
  run_attention<128>(h2, a2w, a2b, o2, S.cs2, S, stream);

  // ---- output layer: out = normalize(relu(o2) @ W3 + b3) ----
  mgemm_kernel<128, 64, true, true><<<dim3(NN / 16, 64 / 64), 256, 0, stream>>>(
      o2, S.w3h, S.w3l, b3, out);
}